// Round 2
// baseline (1824.781 us; speedup 1.0000x reference)
//
#include <hip/hip_runtime.h>

#define N_NODES 131072
#define N_EDGES 1048576
#define N_GRAPHS 1024
#define EMB 96
#define HID 64
#define CAP 64   // max in-degree stored; Poisson(8) => P(deg>=64) ~ 1e-40

// h = x @ W. 8 rows per wave, 32 rows per block. x held in registers,
// broadcast via __shfl with literal lane (compiles to v_readlane).
__global__ __launch_bounds__(256) void k_linear(const float* __restrict__ x,
    const float* __restrict__ W, const float* __restrict__ att_src,
    const float* __restrict__ att_dst, float* __restrict__ h,
    float* __restrict__ a_s, float* __restrict__ a_d)
{
    __shared__ float Wl[EMB * HID];   // 24.6 KB
    int tid = threadIdx.x;
    int c = tid & 63;
    int wid = tid >> 6;
    int row0 = blockIdx.x * 32 + wid * 8;
    for (int t = tid; t < EMB * HID; t += 256) Wl[t] = W[t];

    float xa[8], xb[8];
    #pragma unroll
    for (int r = 0; r < 8; ++r) {
        xa[r] = x[(size_t)(row0 + r) * EMB + c];
        xb[r] = (c < 32) ? x[(size_t)(row0 + r) * EMB + 64 + c] : 0.f;
    }
    __syncthreads();

    float acc[8] = {0.f, 0.f, 0.f, 0.f, 0.f, 0.f, 0.f, 0.f};
    #pragma unroll
    for (int k = 0; k < 64; ++k) {
        float wv = Wl[k * HID + c];
        #pragma unroll
        for (int r = 0; r < 8; ++r)
            acc[r] += __shfl(xa[r], k, 64) * wv;
    }
    #pragma unroll
    for (int k = 0; k < 32; ++k) {
        float wv = Wl[(64 + k) * HID + c];
        #pragma unroll
        for (int r = 0; r < 8; ++r)
            acc[r] += __shfl(xb[r], k, 64) * wv;
    }

    float asv = att_src[c], adv = att_dst[c];
    #pragma unroll
    for (int r = 0; r < 8; ++r) {
        h[(size_t)(row0 + r) * HID + c] = acc[r];
        float s1 = acc[r] * asv;
        float s2 = acc[r] * adv;
        #pragma unroll
        for (int off = 32; off >= 1; off >>= 1) {
            s1 += __shfl_xor(s1, off, 64);
            s2 += __shfl_xor(s2, off, 64);
        }
        if (c == 0) { a_s[row0 + r] = s1; a_d[row0 + r] = s2; }
    }
}

// Build fixed-capacity CSR grouped by dst.
__global__ __launch_bounds__(256) void k_build(const int* __restrict__ src,
    const int* __restrict__ dst, int* __restrict__ cnt, int* __restrict__ slots)
{
    int e = blockIdx.x * 256 + threadIdx.x;
    if (e < N_EDGES) {
        int d = dst[e];
        int slot = atomicAdd(&cnt[d], 1);
        if (slot < CAP) slots[(size_t)d * CAP + slot] = src[e];
    }
}

// One wave per node. All slots loaded in ONE coalesced read (lane j = slot j),
// ONE a_s gather, weights per-lane + wave-reduced z, then 4-wide unrolled
// h-row gathers (independent loads -> MLP). Streams out[] (no pool atomics).
__global__ __launch_bounds__(256) void k_accum(const float* __restrict__ h,
    const float* __restrict__ a_s, const float* __restrict__ a_d,
    const int* __restrict__ cnt, const int* __restrict__ slots,
    const float* __restrict__ bias, float* __restrict__ out)
{
    int tid = threadIdx.x;
    int lane = tid & 63;
    int node = blockIdx.x * 4 + (tid >> 6);
    int deg = cnt[node]; if (deg > CAP) deg = CAP;
    float adi = a_d[node];
    float asi = a_s[node];

    int s_raw = slots[(size_t)node * CAP + lane];   // one coalesced 256B read
    int s_j = (lane < deg) ? s_raw : node;          // safe index for idle lanes
    float t = a_s[s_j] + adi;                       // one gather
    t = t > 0.f ? t : 0.2f * t;
    float w_j = (lane < deg) ? __expf(t) : 0.f;

    // self-loop
    float t0 = asi + adi;
    t0 = t0 > 0.f ? t0 : 0.2f * t0;
    float w0 = __expf(t0);

    float z = w_j;
    #pragma unroll
    for (int off = 32; off >= 1; off >>= 1) z += __shfl_xor(z, off, 64);
    z += w0;

    float acc = w0 * h[(size_t)node * HID + lane];

    int iters = (deg + 3) >> 2;
    for (int it = 0; it < iters; ++it) {
        int j = it * 4;
        int i0 = __shfl(s_j, j,     64);
        int i1 = __shfl(s_j, j + 1, 64);
        int i2 = __shfl(s_j, j + 2, 64);
        int i3 = __shfl(s_j, j + 3, 64);
        float w0_ = __shfl(w_j, j,     64);
        float w1_ = __shfl(w_j, j + 1, 64);
        float w2_ = __shfl(w_j, j + 2, 64);
        float w3_ = __shfl(w_j, j + 3, 64);
        float h0 = h[(size_t)i0 * HID + lane];   // 4 independent 256B gathers
        float h1 = h[(size_t)i1 * HID + lane];
        float h2 = h[(size_t)i2 * HID + lane];
        float h3 = h[(size_t)i3 * HID + lane];
        acc += w0_ * h0 + w1_ * h1 + w2_ * h2 + w3_ * h3;
    }

    out[(size_t)node * HID + lane] = acc / (z + 1e-16f) + bias[lane];
}

// batch is SORTED: each wave scans 64 consecutive nodes, register-accumulates,
// flushes one atomic per graph transition (~1-2 per wave).
__global__ __launch_bounds__(256) void k_pool(const float* __restrict__ out,
    const int* __restrict__ batch, float* __restrict__ pool,
    float* __restrict__ gcnt)
{
    int lane = threadIdx.x & 63;
    int wv = blockIdx.x * 4 + (threadIdx.x >> 6);
    int base = wv * 64;
    int g_cur = batch[base];
    float acc = 0.f;
    int run = 0;
    for (int i = 0; i < 64; ++i) {
        int n = base + i;
        int g = batch[n];
        float v = out[(size_t)n * HID + lane];
        if (g != g_cur) {
            atomicAdd(&pool[g_cur * HID + lane], acc);
            if (lane == 0) atomicAdd(&gcnt[g_cur], (float)run);
            acc = 0.f; run = 0; g_cur = g;
        }
        acc += v; ++run;
    }
    atomicAdd(&pool[g_cur * HID + lane], acc);
    if (lane == 0) atomicAdd(&gcnt[g_cur], (float)run);
}

// Per-graph mean, FC (64 -> 3), log_softmax. One wave per graph.
__global__ __launch_bounds__(256) void k_head(const float* __restrict__ pool,
    const float* __restrict__ gcnt, const float* __restrict__ fc_w,
    const float* __restrict__ fc_b, float* __restrict__ out)
{
    int tid = threadIdx.x;
    int lane = tid & 63;
    int g = blockIdx.x * 4 + (tid >> 6);
    float p = pool[g * HID + lane] / fmaxf(gcnt[g], 1.0f);
    float l0 = p * fc_w[0 * HID + lane];
    float l1 = p * fc_w[1 * HID + lane];
    float l2 = p * fc_w[2 * HID + lane];
    #pragma unroll
    for (int off = 32; off >= 1; off >>= 1) {
        l0 += __shfl_xor(l0, off, 64);
        l1 += __shfl_xor(l1, off, 64);
        l2 += __shfl_xor(l2, off, 64);
    }
    l0 += fc_b[0]; l1 += fc_b[1]; l2 += fc_b[2];
    float m = fmaxf(l0, fmaxf(l1, l2));
    float lse = m + logf(__expf(l0 - m) + __expf(l1 - m) + __expf(l2 - m));
    if (lane == 0) {
        out[g * 3 + 0] = l0 - lse;
        out[g * 3 + 1] = l1 - lse;
        out[g * 3 + 2] = l2 - lse;
    }
}

extern "C" void kernel_launch(void* const* d_in, const int* in_sizes, int n_in,
                              void* d_out, int out_size, void* d_ws, size_t ws_size,
                              hipStream_t stream)
{
    const float* x        = (const float*)d_in[0];
    const int*   ei       = (const int*)d_in[1];   // [2, E] int32
    const int*   batch    = (const int*)d_in[2];
    const float* W        = (const float*)d_in[3];
    const float* att_src  = (const float*)d_in[4];
    const float* att_dst  = (const float*)d_in[5];
    const float* bias_gat = (const float*)d_in[6];
    const float* fc_w     = (const float*)d_in[7];
    const float* fc_b     = (const float*)d_in[8];
    float* out = (float*)d_out;

    char* ws = (char*)d_ws;
    size_t off = 0;
    auto alloc = [&](size_t bytes) {
        void* p = ws + off;
        off += (bytes + 255) & ~(size_t)255;
        return p;
    };
    float* h     = (float*)alloc((size_t)N_NODES * HID * 4);   // 33.5 MB
    int*   slots = (int*)  alloc((size_t)N_NODES * CAP * 4);   // 33.5 MB
    float* a_s   = (float*)alloc((size_t)N_NODES * 4);
    float* a_d   = (float*)alloc((size_t)N_NODES * 4);
    int*   cnt   = (int*)  alloc((size_t)N_NODES * 4);
    float* pool  = (float*)alloc((size_t)N_GRAPHS * HID * 4);
    float* gcnt  = (float*)alloc((size_t)N_GRAPHS * 4);
    // node-out aliases slots: k_accum reads slots[node*64+lane] before writing
    // out[node*64+lane]; per-node regions are identical & disjoint across waves.
    float* nout  = (float*)slots;

    hipMemsetAsync(cnt, 0, (size_t)N_NODES * 4, stream);
    hipMemsetAsync(pool, 0, (size_t)N_GRAPHS * HID * 4, stream);
    hipMemsetAsync(gcnt, 0, (size_t)N_GRAPHS * 4, stream);

    k_linear<<<N_NODES / 32, 256, 0, stream>>>(x, W, att_src, att_dst, h, a_s, a_d);
    k_build<<<N_EDGES / 256, 256, 0, stream>>>(ei, ei + N_EDGES, cnt, slots);
    k_accum<<<N_NODES / 4, 256, 0, stream>>>(h, a_s, a_d, cnt, slots, bias_gat, nout);
    k_pool<<<N_NODES / 256, 256, 0, stream>>>(nout, batch, pool, gcnt);
    k_head<<<N_GRAPHS / 4, 256, 0, stream>>>(pool, gcnt, fc_w, fc_b, out);
}

// Round 3
// 605.058 us; speedup vs baseline: 3.0159x; 3.0159x over previous
//
#include <hip/hip_runtime.h>

#define N_NODES 131072
#define N_EDGES 1048576
#define N_GRAPHS 1024
#define EMB 96
#define HID 64
#define CAP 64   // max in-degree stored; Poisson(8) => P(deg>=64) ~ 1e-40

// h = x @ W via LDS-tiled GEMM. Block = 64-row tile, 256 threads,
// thread = 4 rows x 4 cols (acc[4][4], ~50 VGPR, no spills).
// Epilogue computes a_s/a_d with a 16-lane xor-reduce.
__global__ __launch_bounds__(256) void k_linear(const float* __restrict__ x,
    const float* __restrict__ W, const float* __restrict__ att_src,
    const float* __restrict__ att_dst, float* __restrict__ h,
    float* __restrict__ a_s, float* __restrict__ a_d)
{
    __shared__ float Wl[EMB * HID];   // [96][64] 24.6 KB
    __shared__ float xs[64 * EMB];    // [64][96] 24.6 KB
    int tid = threadIdx.x;
    int row0 = blockIdx.x * 64;
    const float4* Wg4 = (const float4*)W;
    const float4* xg4 = (const float4*)(x + (size_t)row0 * EMB);
    float4* Wl4 = (float4*)Wl;
    float4* xs4 = (float4*)xs;
    #pragma unroll
    for (int i = 0; i < 6; ++i) {      // 1536 float4 each, flat copy
        Wl4[tid + i * 256] = Wg4[tid + i * 256];
        xs4[tid + i * 256] = xg4[tid + i * 256];
    }
    __syncthreads();

    int c0 = (tid & 15) * 4;
    int r0 = (tid >> 4) * 4;
    float acc[4][4] = {};
    #pragma unroll
    for (int kb = 0; kb < 24; ++kb) {
        int k = kb * 4;
        float4 wv0 = *(const float4*)&Wl[(k + 0) * HID + c0];
        float4 wv1 = *(const float4*)&Wl[(k + 1) * HID + c0];
        float4 wv2 = *(const float4*)&Wl[(k + 2) * HID + c0];
        float4 wv3 = *(const float4*)&Wl[(k + 3) * HID + c0];
        #pragma unroll
        for (int r = 0; r < 4; ++r) {
            float4 xv = *(const float4*)&xs[(r0 + r) * EMB + k];
            acc[r][0] += xv.x * wv0.x + xv.y * wv1.x + xv.z * wv2.x + xv.w * wv3.x;
            acc[r][1] += xv.x * wv0.y + xv.y * wv1.y + xv.z * wv2.y + xv.w * wv3.y;
            acc[r][2] += xv.x * wv0.z + xv.y * wv1.z + xv.z * wv2.z + xv.w * wv3.z;
            acc[r][3] += xv.x * wv0.w + xv.y * wv1.w + xv.z * wv2.w + xv.w * wv3.w;
        }
    }

    float4 av = *(const float4*)&att_src[c0];
    float4 dv = *(const float4*)&att_dst[c0];
    #pragma unroll
    for (int r = 0; r < 4; ++r) {
        float4 o = make_float4(acc[r][0], acc[r][1], acc[r][2], acc[r][3]);
        *(float4*)&h[(size_t)(row0 + r0 + r) * HID + c0] = o;
        float ps = o.x * av.x + o.y * av.y + o.z * av.z + o.w * av.w;
        float pd = o.x * dv.x + o.y * dv.y + o.z * dv.z + o.w * dv.w;
        #pragma unroll
        for (int off = 8; off >= 1; off >>= 1) {   // reduce over 16 col-lanes
            ps += __shfl_xor(ps, off, 64);
            pd += __shfl_xor(pd, off, 64);
        }
        if ((tid & 15) == 0) {
            a_s[row0 + r0 + r] = ps;
            a_d[row0 + r0 + r] = pd;
        }
    }
}

// Build fixed-capacity CSR grouped by dst.
__global__ __launch_bounds__(256) void k_build(const int* __restrict__ src,
    const int* __restrict__ dst, int* __restrict__ cnt, int* __restrict__ slots)
{
    int e = blockIdx.x * 256 + threadIdx.x;
    if (e < N_EDGES) {
        int d = dst[e];
        int slot = atomicAdd(&cnt[d], 1);
        if (slot < CAP) slots[(size_t)d * CAP + slot] = src[e];
    }
}

// One wave per node. All slots loaded in ONE coalesced read (lane j = slot j),
// ONE a_s gather, weights per-lane + wave-reduced z, then 4-wide unrolled
// h-row gathers (independent loads -> MLP). Streams out[] (no pool atomics).
__global__ __launch_bounds__(256) void k_accum(const float* __restrict__ h,
    const float* __restrict__ a_s, const float* __restrict__ a_d,
    const int* __restrict__ cnt, const int* __restrict__ slots,
    const float* __restrict__ bias, float* __restrict__ out)
{
    int tid = threadIdx.x;
    int lane = tid & 63;
    int node = blockIdx.x * 4 + (tid >> 6);
    int deg = cnt[node]; if (deg > CAP) deg = CAP;
    float adi = a_d[node];
    float asi = a_s[node];

    int s_raw = slots[(size_t)node * CAP + lane];   // one coalesced 256B read
    int s_j = (lane < deg) ? s_raw : node;          // safe index for idle lanes
    float t = a_s[s_j] + adi;                       // one gather
    t = t > 0.f ? t : 0.2f * t;
    float w_j = (lane < deg) ? __expf(t) : 0.f;

    // self-loop
    float t0 = asi + adi;
    t0 = t0 > 0.f ? t0 : 0.2f * t0;
    float w0 = __expf(t0);

    float z = w_j;
    #pragma unroll
    for (int off = 32; off >= 1; off >>= 1) z += __shfl_xor(z, off, 64);
    z += w0;

    float acc = w0 * h[(size_t)node * HID + lane];

    int iters = (deg + 3) >> 2;
    for (int it = 0; it < iters; ++it) {
        int j = it * 4;
        int i0 = __shfl(s_j, j,     64);
        int i1 = __shfl(s_j, j + 1, 64);
        int i2 = __shfl(s_j, j + 2, 64);
        int i3 = __shfl(s_j, j + 3, 64);
        float w0_ = __shfl(w_j, j,     64);
        float w1_ = __shfl(w_j, j + 1, 64);
        float w2_ = __shfl(w_j, j + 2, 64);
        float w3_ = __shfl(w_j, j + 3, 64);
        float h0 = h[(size_t)i0 * HID + lane];   // 4 independent 256B gathers
        float h1 = h[(size_t)i1 * HID + lane];
        float h2 = h[(size_t)i2 * HID + lane];
        float h3 = h[(size_t)i3 * HID + lane];
        acc += w0_ * h0 + w1_ * h1 + w2_ * h2 + w3_ * h3;
    }

    out[(size_t)node * HID + lane] = acc / (z + 1e-16f) + bias[lane];
}

// batch is SORTED: each wave scans 64 consecutive nodes, register-accumulates,
// flushes one atomic per graph transition (~1-2 per wave).
__global__ __launch_bounds__(256) void k_pool(const float* __restrict__ out,
    const int* __restrict__ batch, float* __restrict__ pool,
    float* __restrict__ gcnt)
{
    int lane = threadIdx.x & 63;
    int wv = blockIdx.x * 4 + (threadIdx.x >> 6);
    int base = wv * 64;
    int g_cur = batch[base];
    float acc = 0.f;
    int run = 0;
    for (int i = 0; i < 64; ++i) {
        int n = base + i;
        int g = batch[n];
        float v = out[(size_t)n * HID + lane];
        if (g != g_cur) {
            atomicAdd(&pool[g_cur * HID + lane], acc);
            if (lane == 0) atomicAdd(&gcnt[g_cur], (float)run);
            acc = 0.f; run = 0; g_cur = g;
        }
        acc += v; ++run;
    }
    atomicAdd(&pool[g_cur * HID + lane], acc);
    if (lane == 0) atomicAdd(&gcnt[g_cur], (float)run);
}

// Per-graph mean, FC (64 -> 3), log_softmax. One wave per graph.
__global__ __launch_bounds__(256) void k_head(const float* __restrict__ pool,
    const float* __restrict__ gcnt, const float* __restrict__ fc_w,
    const float* __restrict__ fc_b, float* __restrict__ out)
{
    int tid = threadIdx.x;
    int lane = tid & 63;
    int g = blockIdx.x * 4 + (tid >> 6);
    float p = pool[g * HID + lane] / fmaxf(gcnt[g], 1.0f);
    float l0 = p * fc_w[0 * HID + lane];
    float l1 = p * fc_w[1 * HID + lane];
    float l2 = p * fc_w[2 * HID + lane];
    #pragma unroll
    for (int off = 32; off >= 1; off >>= 1) {
        l0 += __shfl_xor(l0, off, 64);
        l1 += __shfl_xor(l1, off, 64);
        l2 += __shfl_xor(l2, off, 64);
    }
    l0 += fc_b[0]; l1 += fc_b[1]; l2 += fc_b[2];
    float m = fmaxf(l0, fmaxf(l1, l2));
    float lse = m + logf(__expf(l0 - m) + __expf(l1 - m) + __expf(l2 - m));
    if (lane == 0) {
        out[g * 3 + 0] = l0 - lse;
        out[g * 3 + 1] = l1 - lse;
        out[g * 3 + 2] = l2 - lse;
    }
}

extern "C" void kernel_launch(void* const* d_in, const int* in_sizes, int n_in,
                              void* d_out, int out_size, void* d_ws, size_t ws_size,
                              hipStream_t stream)
{
    const float* x        = (const float*)d_in[0];
    const int*   ei       = (const int*)d_in[1];   // [2, E] int32
    const int*   batch    = (const int*)d_in[2];
    const float* W        = (const float*)d_in[3];
    const float* att_src  = (const float*)d_in[4];
    const float* att_dst  = (const float*)d_in[5];
    const float* bias_gat = (const float*)d_in[6];
    const float* fc_w     = (const float*)d_in[7];
    const float* fc_b     = (const float*)d_in[8];
    float* out = (float*)d_out;

    char* ws = (char*)d_ws;
    size_t off = 0;
    auto alloc = [&](size_t bytes) {
        void* p = ws + off;
        off += (bytes + 255) & ~(size_t)255;
        return p;
    };
    float* h     = (float*)alloc((size_t)N_NODES * HID * 4);   // 33.5 MB
    int*   slots = (int*)  alloc((size_t)N_NODES * CAP * 4);   // 33.5 MB
    float* a_s   = (float*)alloc((size_t)N_NODES * 4);
    float* a_d   = (float*)alloc((size_t)N_NODES * 4);
    int*   cnt   = (int*)  alloc((size_t)N_NODES * 4);
    float* pool  = (float*)alloc((size_t)N_GRAPHS * HID * 4);
    float* gcnt  = (float*)alloc((size_t)N_GRAPHS * 4);
    // node-out aliases slots: k_accum reads slots[node*64+lane] before writing
    // out[node*64+lane]; per-node regions are identical & disjoint across waves.
    float* nout  = (float*)slots;

    hipMemsetAsync(cnt, 0, (size_t)N_NODES * 4, stream);
    hipMemsetAsync(pool, 0, (size_t)N_GRAPHS * HID * 4, stream);
    hipMemsetAsync(gcnt, 0, (size_t)N_GRAPHS * 4, stream);

    k_linear<<<N_NODES / 64, 256, 0, stream>>>(x, W, att_src, att_dst, h, a_s, a_d);
    k_build<<<N_EDGES / 256, 256, 0, stream>>>(ei, ei + N_EDGES, cnt, slots);
    k_accum<<<N_NODES / 4, 256, 0, stream>>>(h, a_s, a_d, cnt, slots, bias_gat, nout);
    k_pool<<<N_NODES / 256, 256, 0, stream>>>(nout, batch, pool, gcnt);
    k_head<<<N_GRAPHS / 4, 256, 0, stream>>>(pool, gcnt, fc_w, fc_b, out);
}

// Round 4
// 277.494 us; speedup vs baseline: 6.5759x; 2.1804x over previous
//
#include <hip/hip_runtime.h>

#define N_NODES 131072
#define N_EDGES 1048576
#define N_GRAPHS 1024
#define EMB 96
#define HID 64
#define CAP 64        // max in-degree stored; Poisson(8) => P(deg>=64) ~ 1e-40
#define XS_STRIDE 100 // 96 + 4 pad: row stride mod 32 banks = 4 -> only 2-way alias (free)

// h = x @ W via LDS-tiled GEMM. Block = 64-row tile, 256 threads,
// thread = 4 rows x 4 cols. #pragma unroll 2 (NOT full) to keep ~90 VGPRs;
// launch_bounds(256,4) pins allocator <=128 VGPRs (R2/R3 lesson: full unroll
// across LDS loads -> 256 VGPR + scratch spill storm).
__global__ __launch_bounds__(256, 4) void k_linear(const float* __restrict__ x,
    const float* __restrict__ W, const float* __restrict__ att_src,
    const float* __restrict__ att_dst, float* __restrict__ h,
    float* __restrict__ a_s, float* __restrict__ a_d)
{
    __shared__ float Wl[EMB * HID];        // [96][64] 24.6 KB
    __shared__ float xs[64 * XS_STRIDE];   // [64][100] 25.6 KB
    int tid = threadIdx.x;
    int row0 = blockIdx.x * 64;
    const float4* Wg4 = (const float4*)W;
    const float4* xg4 = (const float4*)(x + (size_t)row0 * EMB);
    float4* Wl4 = (float4*)Wl;
    float4* xs4 = (float4*)xs;
    #pragma unroll
    for (int i = 0; i < 6; ++i)            // W: 1536 float4 flat copy
        Wl4[tid + i * 256] = Wg4[tid + i * 256];
    #pragma unroll
    for (int i = 0; i < 6; ++i) {          // x: 64 rows x 24 float4, padded rows
        int t = tid + i * 256;
        int r = t / 24, c = t - r * 24;
        xs4[r * 25 + c] = xg4[t];
    }
    __syncthreads();

    int c0 = (tid & 15) * 4;
    int r0 = (tid >> 4) * 4;
    float acc[4][4] = {};
    #pragma unroll 2
    for (int kb = 0; kb < 24; ++kb) {
        int k = kb * 4;
        float4 wv0 = *(const float4*)&Wl[(k + 0) * HID + c0];
        float4 wv1 = *(const float4*)&Wl[(k + 1) * HID + c0];
        float4 wv2 = *(const float4*)&Wl[(k + 2) * HID + c0];
        float4 wv3 = *(const float4*)&Wl[(k + 3) * HID + c0];
        #pragma unroll
        for (int r = 0; r < 4; ++r) {
            float4 xv = *(const float4*)&xs[(r0 + r) * XS_STRIDE + k];
            acc[r][0] += xv.x * wv0.x + xv.y * wv1.x + xv.z * wv2.x + xv.w * wv3.x;
            acc[r][1] += xv.x * wv0.y + xv.y * wv1.y + xv.z * wv2.y + xv.w * wv3.y;
            acc[r][2] += xv.x * wv0.z + xv.y * wv1.z + xv.z * wv2.z + xv.w * wv3.z;
            acc[r][3] += xv.x * wv0.w + xv.y * wv1.w + xv.z * wv2.w + xv.w * wv3.w;
        }
    }

    float4 av = *(const float4*)&att_src[c0];
    float4 dv = *(const float4*)&att_dst[c0];
    #pragma unroll
    for (int r = 0; r < 4; ++r) {
        float4 o = make_float4(acc[r][0], acc[r][1], acc[r][2], acc[r][3]);
        *(float4*)&h[(size_t)(row0 + r0 + r) * HID + c0] = o;
        float ps = o.x * av.x + o.y * av.y + o.z * av.z + o.w * av.w;
        float pd = o.x * dv.x + o.y * dv.y + o.z * dv.z + o.w * dv.w;
        #pragma unroll
        for (int off = 8; off >= 1; off >>= 1) {   // reduce over 16 col-lanes
            ps += __shfl_xor(ps, off, 64);
            pd += __shfl_xor(pd, off, 64);
        }
        if ((tid & 15) == 0) {
            a_s[row0 + r0 + r] = ps;
            a_d[row0 + r0 + r] = pd;
        }
    }
}

// Build fixed-capacity CSR grouped by dst.
__global__ __launch_bounds__(256) void k_build(const int* __restrict__ src,
    const int* __restrict__ dst, int* __restrict__ cnt, int* __restrict__ slots)
{
    int e = blockIdx.x * 256 + threadIdx.x;
    if (e < N_EDGES) {
        int d = dst[e];
        int slot = atomicAdd(&cnt[d], 1);
        if (slot < CAP) slots[(size_t)d * CAP + slot] = src[e];
    }
}

// One wave per node. All slots loaded in ONE coalesced read (lane j = slot j),
// ONE a_s gather, weights per-lane + wave-reduced z, then 4-wide unrolled
// h-row gathers (independent loads -> MLP). Streams out[] (no pool atomics).
__global__ __launch_bounds__(256) void k_accum(const float* __restrict__ h,
    const float* __restrict__ a_s, const float* __restrict__ a_d,
    const int* __restrict__ cnt, const int* __restrict__ slots,
    const float* __restrict__ bias, float* __restrict__ out)
{
    int tid = threadIdx.x;
    int lane = tid & 63;
    int node = blockIdx.x * 4 + (tid >> 6);
    int deg = cnt[node]; if (deg > CAP) deg = CAP;
    float adi = a_d[node];
    float asi = a_s[node];

    int s_raw = slots[(size_t)node * CAP + lane];   // one coalesced 256B read
    int s_j = (lane < deg) ? s_raw : node;          // safe index for idle lanes
    float t = a_s[s_j] + adi;                       // one gather
    t = t > 0.f ? t : 0.2f * t;
    float w_j = (lane < deg) ? __expf(t) : 0.f;

    // self-loop
    float t0 = asi + adi;
    t0 = t0 > 0.f ? t0 : 0.2f * t0;
    float w0 = __expf(t0);

    float z = w_j;
    #pragma unroll
    for (int off = 32; off >= 1; off >>= 1) z += __shfl_xor(z, off, 64);
    z += w0;

    float acc = w0 * h[(size_t)node * HID + lane];

    int iters = (deg + 3) >> 2;
    for (int it = 0; it < iters; ++it) {
        int j = it * 4;
        int i0 = __shfl(s_j, j,     64);
        int i1 = __shfl(s_j, j + 1, 64);
        int i2 = __shfl(s_j, j + 2, 64);
        int i3 = __shfl(s_j, j + 3, 64);
        float w0_ = __shfl(w_j, j,     64);
        float w1_ = __shfl(w_j, j + 1, 64);
        float w2_ = __shfl(w_j, j + 2, 64);
        float w3_ = __shfl(w_j, j + 3, 64);
        float h0 = h[(size_t)i0 * HID + lane];   // 4 independent 256B gathers
        float h1 = h[(size_t)i1 * HID + lane];
        float h2 = h[(size_t)i2 * HID + lane];
        float h3 = h[(size_t)i3 * HID + lane];
        acc += w0_ * h0 + w1_ * h1 + w2_ * h2 + w3_ * h3;
    }

    out[(size_t)node * HID + lane] = acc / (z + 1e-16f) + bias[lane];
}

// batch is SORTED: each wave scans 64 consecutive nodes, register-accumulates,
// flushes one atomic per graph transition (~1-2 per wave).
__global__ __launch_bounds__(256) void k_pool(const float* __restrict__ out,
    const int* __restrict__ batch, float* __restrict__ pool,
    float* __restrict__ gcnt)
{
    int lane = threadIdx.x & 63;
    int wv = blockIdx.x * 4 + (threadIdx.x >> 6);
    int base = wv * 64;
    int g_cur = batch[base];
    float acc = 0.f;
    int run = 0;
    for (int i = 0; i < 64; ++i) {
        int n = base + i;
        int g = batch[n];
        float v = out[(size_t)n * HID + lane];
        if (g != g_cur) {
            atomicAdd(&pool[g_cur * HID + lane], acc);
            if (lane == 0) atomicAdd(&gcnt[g_cur], (float)run);
            acc = 0.f; run = 0; g_cur = g;
        }
        acc += v; ++run;
    }
    atomicAdd(&pool[g_cur * HID + lane], acc);
    if (lane == 0) atomicAdd(&gcnt[g_cur], (float)run);
}

// Per-graph mean, FC (64 -> 3), log_softmax. One wave per graph.
__global__ __launch_bounds__(256) void k_head(const float* __restrict__ pool,
    const float* __restrict__ gcnt, const float* __restrict__ fc_w,
    const float* __restrict__ fc_b, float* __restrict__ out)
{
    int tid = threadIdx.x;
    int lane = tid & 63;
    int g = blockIdx.x * 4 + (tid >> 6);
    float p = pool[g * HID + lane] / fmaxf(gcnt[g], 1.0f);
    float l0 = p * fc_w[0 * HID + lane];
    float l1 = p * fc_w[1 * HID + lane];
    float l2 = p * fc_w[2 * HID + lane];
    #pragma unroll
    for (int off = 32; off >= 1; off >>= 1) {
        l0 += __shfl_xor(l0, off, 64);
        l1 += __shfl_xor(l1, off, 64);
        l2 += __shfl_xor(l2, off, 64);
    }
    l0 += fc_b[0]; l1 += fc_b[1]; l2 += fc_b[2];
    float m = fmaxf(l0, fmaxf(l1, l2));
    float lse = m + logf(__expf(l0 - m) + __expf(l1 - m) + __expf(l2 - m));
    if (lane == 0) {
        out[g * 3 + 0] = l0 - lse;
        out[g * 3 + 1] = l1 - lse;
        out[g * 3 + 2] = l2 - lse;
    }
}

extern "C" void kernel_launch(void* const* d_in, const int* in_sizes, int n_in,
                              void* d_out, int out_size, void* d_ws, size_t ws_size,
                              hipStream_t stream)
{
    const float* x        = (const float*)d_in[0];
    const int*   ei       = (const int*)d_in[1];   // [2, E] int32
    const int*   batch    = (const int*)d_in[2];
    const float* W        = (const float*)d_in[3];
    const float* att_src  = (const float*)d_in[4];
    const float* att_dst  = (const float*)d_in[5];
    const float* bias_gat = (const float*)d_in[6];
    const float* fc_w     = (const float*)d_in[7];
    const float* fc_b     = (const float*)d_in[8];
    float* out = (float*)d_out;

    char* ws = (char*)d_ws;
    size_t off = 0;
    auto alloc = [&](size_t bytes) {
        void* p = ws + off;
        off += (bytes + 255) & ~(size_t)255;
        return p;
    };
    float* h     = (float*)alloc((size_t)N_NODES * HID * 4);   // 33.5 MB
    int*   slots = (int*)  alloc((size_t)N_NODES * CAP * 4);   // 33.5 MB
    float* a_s   = (float*)alloc((size_t)N_NODES * 4);
    float* a_d   = (float*)alloc((size_t)N_NODES * 4);
    int*   cnt   = (int*)  alloc((size_t)N_NODES * 4);
    float* pool  = (float*)alloc((size_t)N_GRAPHS * HID * 4);
    float* gcnt  = (float*)alloc((size_t)N_GRAPHS * 4);
    // node-out aliases slots: k_accum reads slots[node*64+lane] before writing
    // out[node*64+lane]; per-node regions are identical & disjoint across waves.
    float* nout  = (float*)slots;

    hipMemsetAsync(cnt, 0, (size_t)N_NODES * 4, stream);
    hipMemsetAsync(pool, 0, (size_t)N_GRAPHS * HID * 4, stream);
    hipMemsetAsync(gcnt, 0, (size_t)N_GRAPHS * 4, stream);

    k_linear<<<N_NODES / 64, 256, 0, stream>>>(x, W, att_src, att_dst, h, a_s, a_d);
    k_build<<<N_EDGES / 256, 256, 0, stream>>>(ei, ei + N_EDGES, cnt, slots);
    k_accum<<<N_NODES / 4, 256, 0, stream>>>(h, a_s, a_d, cnt, slots, bias_gat, nout);
    k_pool<<<N_NODES / 256, 256, 0, stream>>>(nout, batch, pool, gcnt);
    k_head<<<N_GRAPHS / 4, 256, 0, stream>>>(pool, gcnt, fc_w, fc_b, out);
}